// Round 3
// baseline (1443.618 us; speedup 1.0000x reference)
//
#include <hip/hip_runtime.h>
#include <hip/hip_bf16.h>

typedef __bf16 bf16_t;
typedef bf16_t bf16x8 __attribute__((ext_vector_type(8)));
typedef float f32x4 __attribute__((ext_vector_type(4)));

static constexpr int NCn = 100000;
static constexpr int NPn = 50000;
static constexpr int NE  = 500000;

// Dual-dtype input load: inputs may be fp32 or bf16 (runtime-detected flag).
__device__ __forceinline__ float ldin(const void* p, size_t i, int fp32) {
    return fp32 ? ((const float*)p)[i] : (float)((const bf16_t*)p)[i];
}

// Detect input float width. Read first 512 elements of x as bf16: if the data
// is really fp32, even-indexed bf16 words are fp32-mantissa bits -> random
// exponents -> some |v| > 1e4 with probability ~1. True bf16 N(0,1) data
// never exceeds ~10. NaN patterns also trip the !(range) check.
__global__ __launch_bounds__(64) void detect_dtype(const void* x, int* flag) {
    const bf16_t* xb = (const bf16_t*)x;
    int lane = threadIdx.x;
    int bad = 0;
    for (int i = lane; i < 512; i += 64) {
        float v = (float)xb[i];
        if (!(v > -1e4f && v < 1e4f)) bad = 1;
    }
    unsigned long long m = __ballot(bad);
    if (lane == 0) flag[0] = (m != 0ull) ? 1 : 0;
}

// Fold dst-projection against attention vector: V[k,h] = sum_c W[k,h*C+c]*att[h,c]
// so that a_d = X @ V (the dst projection is never needed elsewhere).
__global__ __launch_bounds__(256) void prep_V(const int* __restrict__ flag,
                                              const void* w1bd, const void* a1bd,
                                              const void* w1rd, const void* a1rd,
                                              const void* w2bd, const void* a2bd,
                                              const void* w2rd, const void* a2rd,
                                              float* V1bd, float* V1rd,
                                              float* V2bd, float* V2rd) {
    int fp32 = flag[0];
    int t = threadIdx.x;
    for (int idx = t; idx < 256; idx += 256) {          // V1bd: k<128, h<2
        int k = idx >> 1, h = idx & 1;
        float s = 0.f;
        for (int c = 0; c < 64; ++c)
            s += ldin(w1bd, (size_t)k * 128 + h * 64 + c, fp32) * ldin(a1bd, h * 64 + c, fp32);
        V1bd[k * 2 + h] = s;
    }
    for (int idx = t; idx < 512; idx += 256) {          // V1rd: k<256, h<2
        int k = idx >> 1, h = idx & 1;
        float s = 0.f;
        for (int c = 0; c < 64; ++c)
            s += ldin(w1rd, (size_t)k * 128 + h * 64 + c, fp32) * ldin(a1rd, h * 64 + c, fp32);
        V1rd[k * 2 + h] = s;
    }
    for (int k = t; k < 128; k += 256) {                // V2bd: k<128, h=0
        float s = 0.f;
        for (int c = 0; c < 64; ++c)
            s += ldin(w2bd, (size_t)k * 64 + c, fp32) * ldin(a2bd, c, fp32);
        V2bd[k] = s;
    }
    for (int k = t; k < 128; k += 256) {                // V2rd
        float s = 0.f;
        for (int c = 0; c < 64; ++c)
            s += ldin(w2rd, (size_t)k * 64 + c, fp32) * ldin(a2rd, c, fp32);
        V2rd[k] = s;
    }
}

// ---------------- GEMM: C[M,N] = A[M,K] @ W[K,N], dual-dtype in, bf16 out ----
template<int K>
__global__ __launch_bounds__(256) void gemm_mfma(const void* __restrict__ A,
                                                 const void* __restrict__ W,
                                                 bf16_t* __restrict__ C,
                                                 int M, int N,
                                                 const int* __restrict__ flag, int allowA) {
    const int fpW = flag[0];
    const int fpA = fpW & allowA;
    constexpr int KP = K + 8;                         // +8 bf16 (=16B) keeps 16B alignment
    __shared__ alignas(16) bf16_t Wt[64 * KP];        // W^T slice: [n][k]
    const int n0 = blockIdx.y * 64;
    for (int i = threadIdx.x; i < 64 * K; i += 256) {
        int k = i >> 6;
        int n = i & 63;
        Wt[n * KP + k] = (bf16_t)ldin(W, (size_t)k * N + n0 + n, fpW);
    }
    __syncthreads();
    const int wave = threadIdx.x >> 6;
    const int lane = threadIdx.x & 63;
    const int lm = lane & 15;
    const int lq = lane >> 4;
    int row = blockIdx.x * 64 + wave * 16 + lm;
    if (row > M - 1) row = M - 1;                     // tail clamp (stores masked)
    f32x4 acc[4] = {};
#pragma unroll
    for (int kt = 0; kt < K / 32; ++kt) {
        bf16x8 a;
        if (fpA) {
            const float* Af = (const float*)A + (size_t)row * K + kt * 32 + lq * 8;
            f32x4 a0 = *(const f32x4*)Af;
            f32x4 a1 = *(const f32x4*)(Af + 4);
#pragma unroll
            for (int j = 0; j < 4; ++j) { a[j] = (bf16_t)a0[j]; a[4 + j] = (bf16_t)a1[j]; }
        } else {
            a = *(const bf16x8*)((const bf16_t*)A + (size_t)row * K + kt * 32 + lq * 8);
        }
#pragma unroll
        for (int nt = 0; nt < 4; ++nt) {
            bf16x8 b = *(const bf16x8*)(&Wt[(nt * 16 + lm) * KP + kt * 32 + lq * 8]);
            acc[nt] = __builtin_amdgcn_mfma_f32_16x16x32_bf16(a, b, acc[nt], 0, 0, 0);
        }
    }
    const int crow0 = blockIdx.x * 64 + wave * 16 + lq * 4;
#pragma unroll
    for (int nt = 0; nt < 4; ++nt) {
        int col = n0 + nt * 16 + lm;
#pragma unroll
        for (int i = 0; i < 4; ++i) {
            int r = crow0 + i;
            if (r < M) C[(size_t)r * N + col] = (bf16_t)acc[nt][i];
        }
    }
}

// ---------------- a_s = sum_c h[n,h,c]*att[h,c] : one wave per node (h in ws bf16) --
__global__ __launch_bounds__(256) void att_dot(const bf16_t* __restrict__ Hb,
                                               const void* __restrict__ att,
                                               float* __restrict__ out,
                                               int Nn, int HD, int H,
                                               const int* __restrict__ flag) {
    int fp32 = flag[0];
    int wid = (blockIdx.x * 256 + threadIdx.x) >> 6;
    int lane = threadIdx.x & 63;
    if (wid >= Nn) return;
    const bf16_t* hp = Hb + (size_t)wid * HD;
    float p0 = (float)hp[lane] * ldin(att, lane, fp32);
    float p1 = 0.f;
    if (HD > 64) p1 = (float)hp[64 + lane] * ldin(att, 64 + lane, fp32);
    for (int off = 32; off; off >>= 1) {
        p0 += __shfl_down(p0, off);
        p1 += __shfl_down(p1, off);
    }
    if (lane == 0) {
        out[(size_t)wid * H] = p0;
        if (H == 2) out[(size_t)wid * H + 1] = p1;
    }
}

// ---------------- a_d[n,h] = sum_k X[n,k]*V[k,h] : one wave per node -----------
__global__ __launch_bounds__(256) void gemv_att(const void* __restrict__ X,
                                                const float* __restrict__ V,
                                                float* __restrict__ out,
                                                int Nn, int K, int H,
                                                const int* __restrict__ flag, int allow) {
    int fp32 = flag[0] & allow;
    int wid = (blockIdx.x * 256 + threadIdx.x) >> 6;
    int lane = threadIdx.x & 63;
    if (wid >= Nn) return;
    float a0 = 0.f, a1 = 0.f;
    for (int k = lane; k < K; k += 64) {
        float x = ldin(X, (size_t)wid * K + k, fp32);
        if (H == 2) { a0 += x * V[k * 2]; a1 += x * V[k * 2 + 1]; }
        else a0 += x * V[k];
    }
    for (int off = 32; off; off >>= 1) {
        a0 += __shfl_down(a0, off);
        a1 += __shfl_down(a1, off);
    }
    if (lane == 0) {
        out[(size_t)wid * H] = a0;
        if (H == 2) out[(size_t)wid * H + 1] = a1;
    }
}

// per edge: ex = exp(leaky(a_s[s]+a_d[d])); den[d] += ex  (softmax w/o max-sub:
// mathematically identical and alpha is bounded << 88 for sane data; fmin is insurance)
__global__ __launch_bounds__(256) void edge_pass12(const int* __restrict__ es,
                                                   const int* __restrict__ ed,
                                                   const float* __restrict__ as_,
                                                   const float* __restrict__ ad_,
                                                   float* __restrict__ ex,
                                                   float* __restrict__ den,
                                                   int E, int H) {
    int e = blockIdx.x * 256 + threadIdx.x;
    if (e >= E) return;
    int s = es[e], d = ed[e];
    for (int h = 0; h < H; ++h) {
        float v = as_[s * H + h] + ad_[d * H + h];
        v = v > 0.f ? v : 0.2f * v;             // leaky_relu slope 0.2
        v = fminf(v, 60.f);
        float x = __expf(v);
        ex[(size_t)e * H + h] = x;
        atomicAdd(&den[d * H + h], x);
    }
}

// wave per edge: out[dst] += h_src[src] * ex/(den+1e-16)
__global__ __launch_bounds__(256) void edge_pass3(const int* __restrict__ es,
                                                  const int* __restrict__ ed,
                                                  const float* __restrict__ ex,
                                                  const float* __restrict__ den,
                                                  const bf16_t* __restrict__ Hsrc,
                                                  float* __restrict__ outacc,
                                                  int E, int H, int HD) {
    int wid = (blockIdx.x * 256 + threadIdx.x) >> 6;
    if (wid >= E) return;
    int lane = threadIdx.x & 63;
    int s = es[wid], d = ed[wid];
    for (int c = lane; c < HD; c += 64) {
        int h = c >> 6;                          // HID = 64
        float w = ex[(size_t)wid * H + h] / (den[(size_t)d * H + h] + 1e-16f);
        float v = (float)Hsrc[(size_t)s * HD + c] * w;
        atomicAdd(&outacc[(size_t)d * HD + c], v);
    }
}

__global__ __launch_bounds__(256) void fin_relu(const float* __restrict__ acc,
                                                const void* __restrict__ bias,
                                                bf16_t* __restrict__ out,
                                                size_t n, int HDm1,
                                                const int* __restrict__ flag) {
    size_t i = (size_t)blockIdx.x * 256 + threadIdx.x;
    if (i >= n) return;
    float v = acc[i] + ldin(bias, i & HDm1, flag[0]);
    out[i] = (bf16_t)fmaxf(v, 0.f);
}

__global__ __launch_bounds__(256) void fin_out(const float* __restrict__ acc,
                                               const void* __restrict__ bias,
                                               void* __restrict__ outbase, size_t base,
                                               size_t n, int HDm1,
                                               const int* __restrict__ flag) {
    int fp32 = flag[0];
    size_t i = (size_t)blockIdx.x * 256 + threadIdx.x;
    if (i >= n) return;
    float v = acc[i] + ldin(bias, i & HDm1, fp32);
    if (fp32) ((float*)outbase)[base + i] = v;
    else      ((bf16_t*)outbase)[base + i] = (bf16_t)v;
}

extern "C" void kernel_launch(void* const* d_in, const int* in_sizes, int n_in,
                              void* d_out, int out_size, void* d_ws, size_t ws_size,
                              hipStream_t stream) {
    const void* xc = d_in[0];
    const void* xp = d_in[1];
    const int* esrc = (const int*)d_in[2];
    const int* edst = (const int*)d_in[3];
    const void* w1b_src = d_in[4];
    const void* w1b_dst = d_in[5];
    const void* a1b_src = d_in[6];
    const void* a1b_dst = d_in[7];
    const void* b1b     = d_in[8];
    const void* w1r_src = d_in[9];
    const void* w1r_dst = d_in[10];
    const void* a1r_src = d_in[11];
    const void* a1r_dst = d_in[12];
    const void* b1r     = d_in[13];
    const void* w2b_src = d_in[14];
    const void* w2b_dst = d_in[15];
    const void* a2b_src = d_in[16];
    const void* a2b_dst = d_in[17];
    const void* b2b     = d_in[18];
    const void* w2r_src = d_in[19];
    const void* w2r_dst = d_in[20];
    const void* a2r_src = d_in[21];
    const void* a2r_dst = d_in[22];
    const void* b2r     = d_in[23];

    // -------- workspace layout (~122 MB, heavily aliased) --------
    char* p = (char*)d_ws;
    auto alloc = [&](size_t nbytes) {
        char* r = p;
        p += (nbytes + 255) & ~(size_t)255;
        return r;
    };
    int* flag = (int*)alloc(256);
    char* regA = alloc((size_t)NCn * 128 * 2);   // Hc (L1 src proj) -> c1
    char* regB = alloc((size_t)NPn * 128 * 2);   // Hp (L1 src proj) -> p1
    char* regC = alloc((size_t)NPn * 128 * 4);   // accP (f32) -> Hc2 + Hp2 (bf16)
    char* regD = alloc((size_t)NCn * 128 * 4);   // accC (f32) -> accP2 + accC2 (f32)
    float* as_s = (float*)alloc((size_t)NCn * 2 * 4);
    float* ad_d = (float*)alloc((size_t)NCn * 2 * 4);
    float* den  = (float*)alloc((size_t)NCn * 2 * 4);
    float* exv  = (float*)alloc((size_t)NE * 2 * 4);
    float* V1bd = (float*)alloc(256 * 4);
    float* V1rd = (float*)alloc(512 * 4);
    float* V2bd = (float*)alloc(128 * 4);
    float* V2rd = (float*)alloc(128 * 4);

    bf16_t* Hc  = (bf16_t*)regA;                 // NC x 128
    bf16_t* Hp  = (bf16_t*)regB;                 // NP x 128
    float*  accP = (float*)regC;                 // NP x 128
    float*  accC = (float*)regD;                 // NC x 128
    bf16_t* c1  = (bf16_t*)regA;                 // overwrites Hc after last read
    bf16_t* p1  = (bf16_t*)regB;                 // overwrites Hp after last read
    bf16_t* Hc2 = (bf16_t*)regC;                 // NC x 64 (after accP consumed)
    bf16_t* Hp2 = (bf16_t*)(regC + (size_t)NCn * 64 * 2);  // NP x 64
    float*  accP2 = (float*)regD;                // NP x 64 (after accC consumed)
    float*  accC2 = (float*)(regD + (size_t)NPn * 64 * 4); // NC x 64

    const dim3 blk(256);
    const int gC = (NCn + 63) / 64, gP = (NPn + 63) / 64;
    const int gE1 = (NE + 255) / 256;
    const int gE64 = (NE + 3) / 4;
    const int gWC = (NCn * 64 + 255) / 256;      // wave-per-node grids
    const int gWP = (NPn * 64 + 255) / 256;

    detect_dtype<<<1, 64, 0, stream>>>(xc, flag);
    prep_V<<<1, 256, 0, stream>>>(flag, w1b_dst, a1b_dst, w1r_dst, a1r_dst,
                                  w2b_dst, a2b_dst, w2r_dst, a2r_dst,
                                  V1bd, V1rd, V2bd, V2rd);

    // ---------------- layer 1 src projections ----------------
    gemm_mfma<256><<<dim3(gC, 2), blk, 0, stream>>>(xc, w1b_src, Hc, NCn, 128, flag, 1);
    gemm_mfma<128><<<dim3(gP, 2), blk, 0, stream>>>(xp, w1r_src, Hp, NPn, 128, flag, 1);

    // ---- L1 dir b (customer -> product), dst segments over edge_dst (NP) ----
    att_dot<<<(NCn + 3) / 4, blk, 0, stream>>>(Hc, a1b_src, as_s, NCn, 128, 2, flag);
    gemv_att<<<gWP, blk, 0, stream>>>(xp, V1bd, ad_d, NPn, 128, 2, flag, 1);
    hipMemsetAsync(den, 0, (size_t)NPn * 2 * 4, stream);
    hipMemsetAsync(accP, 0, (size_t)NPn * 128 * 4, stream);
    edge_pass12<<<gE1, blk, 0, stream>>>(esrc, edst, as_s, ad_d, exv, den, NE, 2);
    edge_pass3<<<gE64, blk, 0, stream>>>(esrc, edst, exv, den, Hc, accP, NE, 2, 128);

    // ---- L1 dir r (product -> customer), dst segments over edge_src (NC) ----
    att_dot<<<(NPn + 3) / 4, blk, 0, stream>>>(Hp, a1r_src, as_s, NPn, 128, 2, flag);
    gemv_att<<<gWC, blk, 0, stream>>>(xc, V1rd, ad_d, NCn, 256, 2, flag, 1);
    hipMemsetAsync(den, 0, (size_t)NCn * 2 * 4, stream);
    hipMemsetAsync(accC, 0, (size_t)NCn * 128 * 4, stream);
    edge_pass12<<<gE1, blk, 0, stream>>>(edst, esrc, as_s, ad_d, exv, den, NE, 2);
    edge_pass3<<<gE64, blk, 0, stream>>>(edst, esrc, exv, den, Hp, accC, NE, 2, 128);

    fin_relu<<<(int)(((size_t)NPn * 128 + 255) / 256), blk, 0, stream>>>(accP, b1b, p1, (size_t)NPn * 128, 127, flag);
    fin_relu<<<(int)(((size_t)NCn * 128 + 255) / 256), blk, 0, stream>>>(accC, b1r, c1, (size_t)NCn * 128, 127, flag);

    // ---------------- layer 2 src projections (ws bf16 inputs -> allowA=0) ----
    gemm_mfma<128><<<dim3(gC, 1), blk, 0, stream>>>(c1, w2b_src, Hc2, NCn, 64, flag, 0);
    gemm_mfma<128><<<dim3(gP, 1), blk, 0, stream>>>(p1, w2r_src, Hp2, NPn, 64, flag, 0);

    // ---- L2 dir b -> p2 ----
    att_dot<<<(NCn + 3) / 4, blk, 0, stream>>>(Hc2, a2b_src, as_s, NCn, 64, 1, flag);
    gemv_att<<<gWP, blk, 0, stream>>>(p1, V2bd, ad_d, NPn, 128, 1, flag, 0);
    hipMemsetAsync(den, 0, (size_t)NPn * 4, stream);
    hipMemsetAsync(accP2, 0, (size_t)NPn * 64 * 4, stream);
    edge_pass12<<<gE1, blk, 0, stream>>>(esrc, edst, as_s, ad_d, exv, den, NE, 1);
    edge_pass3<<<gE64, blk, 0, stream>>>(esrc, edst, exv, den, Hc2, accP2, NE, 1, 64);

    // ---- L2 dir r -> c2 ----
    att_dot<<<(NPn + 3) / 4, blk, 0, stream>>>(Hp2, a2r_src, as_s, NPn, 64, 1, flag);
    gemv_att<<<gWC, blk, 0, stream>>>(c1, V2rd, ad_d, NCn, 128, 1, flag, 0);
    hipMemsetAsync(den, 0, (size_t)NCn * 4, stream);
    hipMemsetAsync(accC2, 0, (size_t)NCn * 64 * 4, stream);
    edge_pass12<<<gE1, blk, 0, stream>>>(edst, esrc, as_s, ad_d, exv, den, NE, 1);
    edge_pass3<<<gE64, blk, 0, stream>>>(edst, esrc, exv, den, Hp2, accC2, NE, 1, 64);

    // ---------------- outputs: c2 then p2 (+bias), dtype per flag ----------------
    fin_out<<<(int)(((size_t)NCn * 64 + 255) / 256), blk, 0, stream>>>(accC2, b2r, d_out, 0, (size_t)NCn * 64, 63, flag);
    fin_out<<<(int)(((size_t)NPn * 64 + 255) / 256), blk, 0, stream>>>(accP2, b2b, d_out, (size_t)NCn * 64, (size_t)NPn * 64, 63, flag);
}

// Round 4
// 952.758 us; speedup vs baseline: 1.5152x; 1.5152x over previous
//
#include <hip/hip_runtime.h>
#include <hip/hip_bf16.h>

typedef __bf16 bf16_t;
typedef bf16_t bf16x2 __attribute__((ext_vector_type(2)));
typedef bf16_t bf16x8 __attribute__((ext_vector_type(8)));
typedef float f32x4 __attribute__((ext_vector_type(4)));

static constexpr int NCn = 100000;
static constexpr int NPn = 50000;
static constexpr int NE  = 500000;

// Dual-dtype input load: inputs may be fp32 or bf16 (runtime-detected flag).
__device__ __forceinline__ float ldin(const void* p, size_t i, int fp32) {
    return fp32 ? ((const float*)p)[i] : (float)((const bf16_t*)p)[i];
}

__global__ __launch_bounds__(64) void detect_dtype(const void* x, int* flag) {
    const bf16_t* xb = (const bf16_t*)x;
    int lane = threadIdx.x;
    int bad = 0;
    for (int i = lane; i < 512; i += 64) {
        float v = (float)xb[i];
        if (!(v > -1e4f && v < 1e4f)) bad = 1;
    }
    unsigned long long m = __ballot(bad);
    if (lane == 0) flag[0] = (m != 0ull) ? 1 : 0;
}

// Fold dst-projection against attention vector: V[k,h] = sum_c W[k,h*C+c]*att[h,c]
__global__ __launch_bounds__(256) void prep_V(const int* __restrict__ flag,
                                              const void* w1bd, const void* a1bd,
                                              const void* w1rd, const void* a1rd,
                                              const void* w2bd, const void* a2bd,
                                              const void* w2rd, const void* a2rd,
                                              float* V1bd, float* V1rd,
                                              float* V2bd, float* V2rd) {
    int fp32 = flag[0];
    int t = threadIdx.x;
    for (int idx = t; idx < 256; idx += 256) {          // V1bd: k<128, h<2
        int k = idx >> 1, h = idx & 1;
        float s = 0.f;
        for (int c = 0; c < 64; ++c)
            s += ldin(w1bd, (size_t)k * 128 + h * 64 + c, fp32) * ldin(a1bd, h * 64 + c, fp32);
        V1bd[k * 2 + h] = s;
    }
    for (int idx = t; idx < 512; idx += 256) {          // V1rd: k<256, h<2
        int k = idx >> 1, h = idx & 1;
        float s = 0.f;
        for (int c = 0; c < 64; ++c)
            s += ldin(w1rd, (size_t)k * 128 + h * 64 + c, fp32) * ldin(a1rd, h * 64 + c, fp32);
        V1rd[k * 2 + h] = s;
    }
    for (int k = t; k < 128; k += 256) {                // V2bd
        float s = 0.f;
        for (int c = 0; c < 64; ++c)
            s += ldin(w2bd, (size_t)k * 64 + c, fp32) * ldin(a2bd, c, fp32);
        V2bd[k] = s;
    }
    for (int k = t; k < 128; k += 256) {                // V2rd
        float s = 0.f;
        for (int c = 0; c < 64; ++c)
            s += ldin(w2rd, (size_t)k * 64 + c, fp32) * ldin(a2rd, c, fp32);
        V2rd[k] = s;
    }
}

// ---------------- CSR build: histogram -> hierarchical scan -> scatter --------
__global__ __launch_bounds__(256) void hist_k(const int* __restrict__ dst,
                                              int* __restrict__ cnt, int E) {
    int e = blockIdx.x * 256 + threadIdx.x;
    if (e < E) atomicAdd(&cnt[dst[e]], 1);
}

// per-block exclusive scan over 1024 elems (4/thread); block total -> bsum[b]
__global__ __launch_bounds__(256) void scan_blocks(const int* __restrict__ cnt,
                                                   int* __restrict__ rs,
                                                   int* __restrict__ bsum, int N) {
    int t = threadIdx.x, b = blockIdx.x;
    int base = b * 1024 + t * 4;
    int c[4];
#pragma unroll
    for (int k = 0; k < 4; ++k) { int i = base + k; c[k] = (i < N) ? cnt[i] : 0; }
    int tsum = c[0] + c[1] + c[2] + c[3];
    __shared__ int sd[256];
    sd[t] = tsum;
    __syncthreads();
    for (int off = 1; off < 256; off <<= 1) {
        int x = (t >= off) ? sd[t - off] : 0;
        __syncthreads();
        sd[t] += x;
        __syncthreads();
    }
    int run = sd[t] - tsum;   // exclusive within block
#pragma unroll
    for (int k = 0; k < 4; ++k) { int i = base + k; if (i < N) rs[i] = run; run += c[k]; }
    if (t == 255) bsum[b] = sd[255];
}

__global__ __launch_bounds__(128) void scan_bsum(int* bsum, int nb) {
    int t = threadIdx.x;
    __shared__ int sd[128];
    int v = (t < nb) ? bsum[t] : 0;
    sd[t] = v;
    __syncthreads();
    for (int off = 1; off < 128; off <<= 1) {
        int x = (t >= off) ? sd[t - off] : 0;
        __syncthreads();
        sd[t] += x;
        __syncthreads();
    }
    if (t < nb) bsum[t] = sd[t] - v;   // exclusive
}

__global__ __launch_bounds__(256) void scan_add(int* __restrict__ rs,
                                                const int* __restrict__ bsum,
                                                int N, int E) {
    int i = blockIdx.x * 256 + threadIdx.x;
    if (i < N) rs[i] += bsum[i >> 10];
    if (i == 0) rs[N] = E;
}

// cur pre-loaded with rs (running cursor); srcs[pos] = neighbor id
__global__ __launch_bounds__(256) void scatter_k(const int* __restrict__ dst,
                                                 const int* __restrict__ nbr,
                                                 int* __restrict__ cur,
                                                 int* __restrict__ srcs, int E) {
    int e = blockIdx.x * 256 + threadIdx.x;
    if (e >= E) return;
    int pos = atomicAdd(&cur[dst[e]], 1);
    srcs[pos] = nbr[e];
}

// ---------------- GEMM: C[M,N] = A[M,K] @ W[K,N], dual-dtype in, bf16 out ----
template<int K>
__global__ __launch_bounds__(256) void gemm_mfma(const void* __restrict__ A,
                                                 const void* __restrict__ W,
                                                 bf16_t* __restrict__ C,
                                                 int M, int N,
                                                 const int* __restrict__ flag, int allowA) {
    const int fpW = flag[0];
    const int fpA = fpW & allowA;
    constexpr int KP = K + 8;
    __shared__ alignas(16) bf16_t Wt[64 * KP];
    const int n0 = blockIdx.y * 64;
    for (int i = threadIdx.x; i < 64 * K; i += 256) {
        int k = i >> 6;
        int n = i & 63;
        Wt[n * KP + k] = (bf16_t)ldin(W, (size_t)k * N + n0 + n, fpW);
    }
    __syncthreads();
    const int wave = threadIdx.x >> 6;
    const int lane = threadIdx.x & 63;
    const int lm = lane & 15;
    const int lq = lane >> 4;
    int row = blockIdx.x * 64 + wave * 16 + lm;
    if (row > M - 1) row = M - 1;
    f32x4 acc[4] = {};
#pragma unroll
    for (int kt = 0; kt < K / 32; ++kt) {
        bf16x8 a;
        if (fpA) {
            const float* Af = (const float*)A + (size_t)row * K + kt * 32 + lq * 8;
            f32x4 a0 = *(const f32x4*)Af;
            f32x4 a1 = *(const f32x4*)(Af + 4);
#pragma unroll
            for (int j = 0; j < 4; ++j) { a[j] = (bf16_t)a0[j]; a[4 + j] = (bf16_t)a1[j]; }
        } else {
            a = *(const bf16x8*)((const bf16_t*)A + (size_t)row * K + kt * 32 + lq * 8);
        }
#pragma unroll
        for (int nt = 0; nt < 4; ++nt) {
            bf16x8 b = *(const bf16x8*)(&Wt[(nt * 16 + lm) * KP + kt * 32 + lq * 8]);
            acc[nt] = __builtin_amdgcn_mfma_f32_16x16x32_bf16(a, b, acc[nt], 0, 0, 0);
        }
    }
    const int crow0 = blockIdx.x * 64 + wave * 16 + lq * 4;
#pragma unroll
    for (int nt = 0; nt < 4; ++nt) {
        int col = n0 + nt * 16 + lm;
#pragma unroll
        for (int i = 0; i < 4; ++i) {
            int r = crow0 + i;
            if (r < M) C[(size_t)r * N + col] = (bf16_t)acc[nt][i];
        }
    }
}

// ---------------- a_s = sum_c h[n,h,c]*att[h,c] : one wave per node ----------
__global__ __launch_bounds__(256) void att_dot(const bf16_t* __restrict__ Hb,
                                               const void* __restrict__ att,
                                               float* __restrict__ out,
                                               int Nn, int HD, int H,
                                               const int* __restrict__ flag) {
    int fp32 = flag[0];
    int wid = (blockIdx.x * 256 + threadIdx.x) >> 6;
    int lane = threadIdx.x & 63;
    if (wid >= Nn) return;
    const bf16_t* hp = Hb + (size_t)wid * HD;
    float p0 = (float)hp[lane] * ldin(att, lane, fp32);
    float p1 = 0.f;
    if (HD > 64) p1 = (float)hp[64 + lane] * ldin(att, 64 + lane, fp32);
    for (int off = 32; off; off >>= 1) {
        p0 += __shfl_down(p0, off);
        p1 += __shfl_down(p1, off);
    }
    if (lane == 0) {
        out[(size_t)wid * H] = p0;
        if (H == 2) out[(size_t)wid * H + 1] = p1;
    }
}

// ---------------- a_d[n,h] = sum_k X[n,k]*V[k,h] : one wave per node ---------
__global__ __launch_bounds__(256) void gemv_att(const void* __restrict__ X,
                                                const float* __restrict__ V,
                                                float* __restrict__ out,
                                                int Nn, int K, int H,
                                                const int* __restrict__ flag, int allow) {
    int fp32 = flag[0] & allow;
    int wid = (blockIdx.x * 256 + threadIdx.x) >> 6;
    int lane = threadIdx.x & 63;
    if (wid >= Nn) return;
    float a0 = 0.f, a1 = 0.f;
    for (int k = lane; k < K; k += 64) {
        float x = ldin(X, (size_t)wid * K + k, fp32);
        if (H == 2) { a0 += x * V[k * 2]; a1 += x * V[k * 2 + 1]; }
        else a0 += x * V[k];
    }
    for (int off = 32; off; off >>= 1) {
        a0 += __shfl_down(a0, off);
        a1 += __shfl_down(a1, off);
    }
    if (lane == 0) {
        out[(size_t)wid * H] = a0;
        if (H == 2) out[(size_t)wid * H + 1] = a1;
    }
}

// ---------------- fused segment-softmax + aggregate, wave per destination ----
// HD=128 (2 heads, layer1, MODE0: relu -> ws bf16) or HD=64 (1 head, layer2,
// MODE1: +bias -> d_out in flag dtype). Gathers h_src rows coalesced; writes
// each output row exactly once (no atomics).
template<int HD, int MODE>
__global__ __launch_bounds__(256) void aggregate(const int* __restrict__ rs,
                                                 const int* __restrict__ srcs,
                                                 const float* __restrict__ as_,
                                                 const float* __restrict__ ad_,
                                                 const bf16_t* __restrict__ H,
                                                 const void* __restrict__ bias,
                                                 void* __restrict__ outb, size_t obase,
                                                 int Nd, const int* __restrict__ flag) {
    constexpr int NH = HD / 64;
    int wid = (blockIdx.x * 256 + threadIdx.x) >> 6;
    int lane = threadIdx.x & 63;
    if (wid >= Nd) return;
    int start = rs[wid], end = rs[wid + 1];
    float ad0 = ad_[(size_t)wid * NH];
    float ad1 = (NH == 2) ? ad_[(size_t)wid * NH + 1] : 0.f;
    float den0 = 0.f, den1 = 0.f;
    for (int i = start + lane; i < end; i += 64) {
        int s = srcs[i];
        float v0 = as_[(size_t)s * NH] + ad0;
        v0 = v0 > 0.f ? v0 : 0.2f * v0;
        den0 += __expf(fminf(v0, 60.f));
        if (NH == 2) {
            float v1 = as_[(size_t)s * NH + 1] + ad1;
            v1 = v1 > 0.f ? v1 : 0.2f * v1;
            den1 += __expf(fminf(v1, 60.f));
        }
    }
    for (int off = 32; off; off >>= 1) {
        den0 += __shfl_down(den0, off);
        if (NH == 2) den1 += __shfl_down(den1, off);
    }
    den0 = __shfl(den0, 0);
    float inv0 = 1.f / (den0 + 1e-16f), inv1 = 0.f;
    if (NH == 2) { den1 = __shfl(den1, 0); inv1 = 1.f / (den1 + 1e-16f); }

    float acc0 = 0.f, acc1 = 0.f;
    for (int j = start; j < end; ++j) {
        int s = srcs[j];                    // uniform across wave -> broadcast
        if (NH == 2) {
            float v0 = as_[(size_t)s * 2] + ad0;
            v0 = v0 > 0.f ? v0 : 0.2f * v0;
            float v1 = as_[(size_t)s * 2 + 1] + ad1;
            v1 = v1 > 0.f ? v1 : 0.2f * v1;
            float e0 = __expf(fminf(v0, 60.f)) * inv0;
            float e1 = __expf(fminf(v1, 60.f)) * inv1;
            float w = (lane >> 5) ? e1 : e0;    // lane covers c=2*lane,2*lane+1; head=c>>6
            bf16x2 hv = *(const bf16x2*)(H + (size_t)s * 128 + 2 * lane);
            acc0 += (float)hv[0] * w;
            acc1 += (float)hv[1] * w;
        } else {
            float v0 = as_[s] + ad0;
            v0 = v0 > 0.f ? v0 : 0.2f * v0;
            float w = __expf(fminf(v0, 60.f)) * inv0;
            acc0 += (float)H[(size_t)s * 64 + lane] * w;
        }
    }
    int fp32 = flag[0];
    if (NH == 2) {
        int c0 = 2 * lane;
        float o0 = acc0 + ldin(bias, c0, fp32);
        float o1 = acc1 + ldin(bias, c0 + 1, fp32);
        // MODE0 only for HD=128
        bf16x2 ov;
        ov[0] = (bf16_t)fmaxf(o0, 0.f);
        ov[1] = (bf16_t)fmaxf(o1, 0.f);
        *(bf16x2*)((bf16_t*)outb + (size_t)wid * 128 + c0) = ov;
    } else {
        float o = acc0 + ldin(bias, lane, fp32);
        size_t oi = obase + (size_t)wid * 64 + lane;
        if (MODE == 0) {
            ((bf16_t*)outb)[oi] = (bf16_t)fmaxf(o, 0.f);
        } else {
            if (fp32) ((float*)outb)[oi] = o;
            else      ((bf16_t*)outb)[oi] = (bf16_t)o;
        }
    }
}

extern "C" void kernel_launch(void* const* d_in, const int* in_sizes, int n_in,
                              void* d_out, int out_size, void* d_ws, size_t ws_size,
                              hipStream_t stream) {
    const void* xc = d_in[0];
    const void* xp = d_in[1];
    const int* esrc = (const int*)d_in[2];   // customer ids
    const int* edst = (const int*)d_in[3];   // product ids
    const void* w1b_src = d_in[4];
    const void* a1b_src = d_in[6];
    const void* w1b_dst = d_in[5];
    const void* a1b_dst = d_in[7];
    const void* b1b     = d_in[8];
    const void* w1r_src = d_in[9];
    const void* w1r_dst = d_in[10];
    const void* a1r_src = d_in[11];
    const void* a1r_dst = d_in[12];
    const void* b1r     = d_in[13];
    const void* w2b_src = d_in[14];
    const void* w2b_dst = d_in[15];
    const void* a2b_src = d_in[16];
    const void* a2b_dst = d_in[17];
    const void* b2b     = d_in[18];
    const void* w2r_src = d_in[19];
    const void* w2r_dst = d_in[20];
    const void* a2r_src = d_in[21];
    const void* a2r_dst = d_in[22];
    const void* b2r     = d_in[23];

    char* p = (char*)d_ws;
    auto alloc = [&](size_t nbytes) {
        char* r = p;
        p += (nbytes + 255) & ~(size_t)255;
        return r;
    };
    int* flag   = (int*)alloc(256);
    bf16_t* Hc  = (bf16_t*)alloc((size_t)NCn * 128 * 2);
    bf16_t* Hp  = (bf16_t*)alloc((size_t)NPn * 128 * 2);
    bf16_t* p1  = (bf16_t*)alloc((size_t)NPn * 128 * 2);
    bf16_t* c1  = (bf16_t*)alloc((size_t)NCn * 128 * 2);
    bf16_t* Hc2 = (bf16_t*)alloc((size_t)NCn * 64 * 2);
    bf16_t* Hp2 = (bf16_t*)alloc((size_t)NPn * 64 * 2);
    float* as_s = (float*)alloc((size_t)NCn * 2 * 4);
    float* ad_d = (float*)alloc((size_t)NCn * 2 * 4);
    int* rsB    = (int*)alloc((size_t)(NPn + 1) * 4);
    int* rsR    = (int*)alloc((size_t)(NCn + 1) * 4);
    int* srcsB  = (int*)alloc((size_t)NE * 4);
    int* srcsR  = (int*)alloc((size_t)NE * 4);
    int* cntB   = (int*)alloc((size_t)NPn * 4);      // histogram, then cursor
    int* cntR   = (int*)alloc((size_t)NCn * 4);
    int* bsum   = (int*)alloc(128 * 4);
    float* V1bd = (float*)alloc(256 * 4);
    float* V1rd = (float*)alloc(512 * 4);
    float* V2bd = (float*)alloc(128 * 4);
    float* V2rd = (float*)alloc(128 * 4);

    const dim3 blk(256);
    const int gC = (NCn + 63) / 64, gP = (NPn + 63) / 64;
    const int gE = (NE + 255) / 256;
    const int gWC = (NCn * 64 + 255) / 256;   // wave-per-node grids
    const int gWP = (NPn * 64 + 255) / 256;
    const int sbP = (NPn + 1023) / 1024;      // scan blocks
    const int sbR = (NCn + 1023) / 1024;

    detect_dtype<<<1, 64, 0, stream>>>(xc, flag);
    prep_V<<<1, 256, 0, stream>>>(flag, w1b_dst, a1b_dst, w1r_dst, a1r_dst,
                                  w2b_dst, a2b_dst, w2r_dst, a2r_dst,
                                  V1bd, V1rd, V2bd, V2rd);

    // -------- CSR dir b (dst = product = edst, nbr = esrc) --------
    hipMemsetAsync(cntB, 0, (size_t)NPn * 4, stream);
    hist_k<<<gE, blk, 0, stream>>>(edst, cntB, NE);
    scan_blocks<<<sbP, blk, 0, stream>>>(cntB, rsB, bsum, NPn);
    scan_bsum<<<1, 128, 0, stream>>>(bsum, sbP);
    scan_add<<<(NPn + 256) / 256, blk, 0, stream>>>(rsB, bsum, NPn, NE);
    hipMemcpyAsync(cntB, rsB, (size_t)NPn * 4, hipMemcpyDeviceToDevice, stream);
    scatter_k<<<gE, blk, 0, stream>>>(edst, esrc, cntB, srcsB, NE);

    // -------- CSR dir r (dst = customer = esrc, nbr = edst) --------
    hipMemsetAsync(cntR, 0, (size_t)NCn * 4, stream);
    hist_k<<<gE, blk, 0, stream>>>(esrc, cntR, NE);
    scan_blocks<<<sbR, blk, 0, stream>>>(cntR, rsR, bsum, NCn);
    scan_bsum<<<1, 128, 0, stream>>>(bsum, sbR);
    scan_add<<<(NCn + 256) / 256, blk, 0, stream>>>(rsR, bsum, NCn, NE);
    hipMemcpyAsync(cntR, rsR, (size_t)NCn * 4, hipMemcpyDeviceToDevice, stream);
    scatter_k<<<gE, blk, 0, stream>>>(esrc, edst, cntR, srcsR, NE);

    // -------- layer 1 src projections --------
    gemm_mfma<256><<<dim3(gC, 2), blk, 0, stream>>>(xc, w1b_src, Hc, NCn, 128, flag, 1);
    gemm_mfma<128><<<dim3(gP, 2), blk, 0, stream>>>(xp, w1r_src, Hp, NPn, 128, flag, 1);

    // ---- L1 dir b (customer -> product) ----
    att_dot<<<(NCn + 3) / 4, blk, 0, stream>>>(Hc, a1b_src, as_s, NCn, 128, 2, flag);
    gemv_att<<<gWP, blk, 0, stream>>>(xp, V1bd, ad_d, NPn, 128, 2, flag, 1);
    aggregate<128, 0><<<(NPn + 3) / 4, blk, 0, stream>>>(rsB, srcsB, as_s, ad_d, Hc, b1b, p1, 0, NPn, flag);

    // ---- L1 dir r (product -> customer) ----
    att_dot<<<(NPn + 3) / 4, blk, 0, stream>>>(Hp, a1r_src, as_s, NPn, 128, 2, flag);
    gemv_att<<<gWC, blk, 0, stream>>>(xc, V1rd, ad_d, NCn, 256, 2, flag, 1);
    aggregate<128, 0><<<(NCn + 3) / 4, blk, 0, stream>>>(rsR, srcsR, as_s, ad_d, Hp, b1r, c1, 0, NCn, flag);

    // -------- layer 2 src projections (ws bf16 inputs -> allowA=0) --------
    gemm_mfma<128><<<dim3(gC, 1), blk, 0, stream>>>(c1, w2b_src, Hc2, NCn, 64, flag, 0);
    gemm_mfma<128><<<dim3(gP, 1), blk, 0, stream>>>(p1, w2r_src, Hp2, NPn, 64, flag, 0);

    // ---- L2 dir b -> p2 (second half of d_out) ----
    att_dot<<<(NCn + 3) / 4, blk, 0, stream>>>(Hc2, a2b_src, as_s, NCn, 64, 1, flag);
    gemv_att<<<gWP, blk, 0, stream>>>(p1, V2bd, ad_d, NPn, 128, 1, flag, 0);
    aggregate<64, 1><<<(NPn + 3) / 4, blk, 0, stream>>>(rsB, srcsB, as_s, ad_d, Hc2, b2b, d_out, (size_t)NCn * 64, NPn, flag);

    // ---- L2 dir r -> c2 (first half of d_out) ----
    att_dot<<<(NPn + 3) / 4, blk, 0, stream>>>(Hp2, a2r_src, as_s, NPn, 64, 1, flag);
    gemv_att<<<gWC, blk, 0, stream>>>(c1, V2rd, ad_d, NCn, 128, 1, flag, 0);
    aggregate<64, 1><<<(NCn + 3) / 4, blk, 0, stream>>>(rsR, srcsR, as_s, ad_d, Hp2, b2r, d_out, 0, NCn, flag);
}

// Round 6
// 848.409 us; speedup vs baseline: 1.7016x; 1.1230x over previous
//
#include <hip/hip_runtime.h>
#include <hip/hip_bf16.h>

typedef __bf16 bf16_t;
typedef bf16_t bf16x2 __attribute__((ext_vector_type(2)));
typedef bf16_t bf16x4 __attribute__((ext_vector_type(4)));
typedef bf16_t bf16x8 __attribute__((ext_vector_type(8)));
typedef float f32x2 __attribute__((ext_vector_type(2)));
typedef float f32x4 __attribute__((ext_vector_type(4)));

static constexpr int NCn = 100000;
static constexpr int NPn = 50000;
static constexpr int NE  = 500000;

// Dual-dtype input load: inputs may be fp32 or bf16 (runtime-detected flag).
__device__ __forceinline__ float ldin(const void* p, size_t i, int fp32) {
    return fp32 ? ((const float*)p)[i] : (float)((const bf16_t*)p)[i];
}

__global__ __launch_bounds__(64) void detect_dtype(const void* x, int* flag) {
    const bf16_t* xb = (const bf16_t*)x;
    int lane = threadIdx.x;
    int bad = 0;
    for (int i = lane; i < 512; i += 64) {
        float v = (float)xb[i];
        if (!(v > -1e4f && v < 1e4f)) bad = 1;
    }
    unsigned long long m = __ballot(bad);
    if (lane == 0) flag[0] = (m != 0ull) ? 1 : 0;
}

// ---- tiny utility kernels (replace hipMemsetAsync / hipMemcpyAsync) ---------
__global__ __launch_bounds__(256) void zero_int(int* __restrict__ p, int n) {
    int i = blockIdx.x * 256 + threadIdx.x;
    if (i < n) p[i] = 0;
}
__global__ __launch_bounds__(256) void copy_int(const int* __restrict__ s,
                                                int* __restrict__ d, int n) {
    int i = blockIdx.x * 256 + threadIdx.x;
    if (i < n) d[i] = s[i];
}

// Fold dst-projection against attention vector: V[k,h] = sum_c W[k,h*C+c]*att[h,c]
__global__ __launch_bounds__(256) void prep_V(const int* __restrict__ flag,
                                              const void* w1bd, const void* a1bd,
                                              const void* w1rd, const void* a1rd,
                                              const void* w2bd, const void* a2bd,
                                              const void* w2rd, const void* a2rd,
                                              float* V1bd, float* V1rd,
                                              float* V2bd, float* V2rd) {
    int fp32 = flag[0];
    int t = threadIdx.x;
    for (int idx = t; idx < 256; idx += 256) {          // V1bd: k<128, h<2
        int k = idx >> 1, h = idx & 1;
        float s = 0.f;
        for (int c = 0; c < 64; ++c)
            s += ldin(w1bd, (size_t)k * 128 + h * 64 + c, fp32) * ldin(a1bd, h * 64 + c, fp32);
        V1bd[k * 2 + h] = s;
    }
    for (int idx = t; idx < 512; idx += 256) {          // V1rd: k<256, h<2
        int k = idx >> 1, h = idx & 1;
        float s = 0.f;
        for (int c = 0; c < 64; ++c)
            s += ldin(w1rd, (size_t)k * 128 + h * 64 + c, fp32) * ldin(a1rd, h * 64 + c, fp32);
        V1rd[k * 2 + h] = s;
    }
    for (int k = t; k < 128; k += 256) {                // V2bd
        float s = 0.f;
        for (int c = 0; c < 64; ++c)
            s += ldin(w2bd, (size_t)k * 64 + c, fp32) * ldin(a2bd, c, fp32);
        V2bd[k] = s;
    }
    for (int k = t; k < 128; k += 256) {                // V2rd
        float s = 0.f;
        for (int c = 0; c < 64; ++c)
            s += ldin(w2rd, (size_t)k * 64 + c, fp32) * ldin(a2rd, c, fp32);
        V2rd[k] = s;
    }
}

// Transpose + convert weight W[K][N] (input dtype) -> Wt[N][K] bf16.
__global__ __launch_bounds__(256) void prep_w(const void* __restrict__ W,
                                              bf16_t* __restrict__ Wt,
                                              int N, int ks,
                                              const int* __restrict__ flag) {
    int fp32 = flag[0];
    int idx = blockIdx.x * 256 + threadIdx.x;
    int K = 1 << ks;
    int n = idx >> ks, k = idx & (K - 1);
    if (n < N) Wt[idx] = (bf16_t)ldin(W, (size_t)k * N + n, fp32);
}

// Convert X[M][K] (flag dtype) -> bf16, fused with ad[m,h] = X[m,:] @ V[:,h].
template<int K>
__global__ __launch_bounds__(256) void cvt_rows(const void* __restrict__ X,
                                                bf16_t* __restrict__ Xb,
                                                const float* __restrict__ V,
                                                float* __restrict__ ad,
                                                int M, const int* __restrict__ flag) {
    constexpr int EPL = K / 64;
    int fp32 = flag[0];
    int wid = (blockIdx.x * 256 + threadIdx.x) >> 6;
    int lane = threadIdx.x & 63;
    if (wid >= M) return;
    size_t base = (size_t)wid * K + lane * EPL;
    float x[EPL];
    if constexpr (EPL == 4) {
        if (fp32) { f32x4 t = *(const f32x4*)((const float*)X + base);
#pragma unroll
            for (int j = 0; j < 4; ++j) x[j] = t[j];
        } else { bf16x4 t = *(const bf16x4*)((const bf16_t*)X + base);
#pragma unroll
            for (int j = 0; j < 4; ++j) x[j] = (float)t[j];
        }
        bf16x4 o;
#pragma unroll
        for (int j = 0; j < 4; ++j) o[j] = (bf16_t)x[j];
        *(bf16x4*)(Xb + base) = o;
    } else {
        if (fp32) { f32x2 t = *(const f32x2*)((const float*)X + base);
#pragma unroll
            for (int j = 0; j < 2; ++j) x[j] = t[j];
        } else { bf16x2 t = *(const bf16x2*)((const bf16_t*)X + base);
#pragma unroll
            for (int j = 0; j < 2; ++j) x[j] = (float)t[j];
        }
        bf16x2 o;
#pragma unroll
        for (int j = 0; j < 2; ++j) o[j] = (bf16_t)x[j];
        *(bf16x2*)(Xb + base) = o;
    }
    float a0 = 0.f, a1 = 0.f;
#pragma unroll
    for (int j = 0; j < EPL; ++j) {
        int k = lane * EPL + j;
        a0 += x[j] * V[k * 2];
        a1 += x[j] * V[k * 2 + 1];
    }
    for (int off = 32; off; off >>= 1) {
        a0 += __shfl_down(a0, off);
        a1 += __shfl_down(a1, off);
    }
    if (lane == 0) { ad[(size_t)wid * 2] = a0; ad[(size_t)wid * 2 + 1] = a1; }
}

// ---------------- CSR build: histogram -> hierarchical scan -> scatter --------
__global__ __launch_bounds__(256) void hist_k(const int* __restrict__ dst,
                                              int* __restrict__ cnt, int E) {
    int e = blockIdx.x * 256 + threadIdx.x;
    if (e < E) atomicAdd(&cnt[dst[e]], 1);
}

__global__ __launch_bounds__(256) void scan_blocks(const int* __restrict__ cnt,
                                                   int* __restrict__ rs,
                                                   int* __restrict__ bsum, int N) {
    int t = threadIdx.x, b = blockIdx.x;
    int base = b * 1024 + t * 4;
    int c[4];
#pragma unroll
    for (int k = 0; k < 4; ++k) { int i = base + k; c[k] = (i < N) ? cnt[i] : 0; }
    int tsum = c[0] + c[1] + c[2] + c[3];
    __shared__ int sd[256];
    sd[t] = tsum;
    __syncthreads();
    for (int off = 1; off < 256; off <<= 1) {
        int x = (t >= off) ? sd[t - off] : 0;
        __syncthreads();
        sd[t] += x;
        __syncthreads();
    }
    int run = sd[t] - tsum;
#pragma unroll
    for (int k = 0; k < 4; ++k) { int i = base + k; if (i < N) rs[i] = run; run += c[k]; }
    if (t == 255) bsum[b] = sd[255];
}

__global__ __launch_bounds__(128) void scan_bsum(int* bsum, int nb) {
    int t = threadIdx.x;
    __shared__ int sd[128];
    int v = (t < nb) ? bsum[t] : 0;
    sd[t] = v;
    __syncthreads();
    for (int off = 1; off < 128; off <<= 1) {
        int x = (t >= off) ? sd[t - off] : 0;
        __syncthreads();
        sd[t] += x;
        __syncthreads();
    }
    if (t < nb) bsum[t] = sd[t] - v;
}

__global__ __launch_bounds__(256) void scan_add(int* __restrict__ rs,
                                                const int* __restrict__ bsum,
                                                int N, int E) {
    int i = blockIdx.x * 256 + threadIdx.x;
    if (i < N) rs[i] += bsum[i >> 10];
    if (i == 0) rs[N] = E;
}

__global__ __launch_bounds__(256) void scatter_k(const int* __restrict__ dst,
                                                 const int* __restrict__ nbr,
                                                 int* __restrict__ cur,
                                                 int* __restrict__ srcs, int E) {
    int e = blockIdx.x * 256 + threadIdx.x;
    if (e >= E) return;
    int pos = atomicAdd(&cur[dst[e]], 1);
    srcs[pos] = nbr[e];
}

// ---------------- LDS-free GEMM: C[M,N] = A[M,K] @ Wt[N,K]^T, all bf16 -------
template<int K>
__global__ __launch_bounds__(256) void gemm_nl(const bf16_t* __restrict__ A,
                                               const bf16_t* __restrict__ Wt,
                                               bf16_t* __restrict__ C,
                                               int M, int N) {
    const int w = threadIdx.x >> 6;
    const int lane = threadIdx.x & 63;
    const int lm = lane & 15;
    const int lq = lane >> 4;
    const int n0 = blockIdx.y * 64;
    const int r0 = blockIdx.x * 128 + w * 32;
    int ra0 = r0 + lm;       if (ra0 > M - 1) ra0 = M - 1;
    int ra1 = r0 + 16 + lm;  if (ra1 > M - 1) ra1 = M - 1;
    const bf16_t* A0 = A + (size_t)ra0 * K + lq * 8;
    const bf16_t* A1 = A + (size_t)ra1 * K + lq * 8;
    const bf16_t* B0 = Wt + (size_t)(n0 + lm) * K + lq * 8;
    f32x4 acc[2][4] = {};
#pragma unroll
    for (int kt = 0; kt < K / 32; ++kt) {
        bf16x8 a0 = *(const bf16x8*)(A0 + kt * 32);
        bf16x8 a1 = *(const bf16x8*)(A1 + kt * 32);
#pragma unroll
        for (int nt = 0; nt < 4; ++nt) {
            bf16x8 b = *(const bf16x8*)(B0 + (size_t)nt * 16 * K + kt * 32);
            acc[0][nt] = __builtin_amdgcn_mfma_f32_16x16x32_bf16(a0, b, acc[0][nt], 0, 0, 0);
            acc[1][nt] = __builtin_amdgcn_mfma_f32_16x16x32_bf16(a1, b, acc[1][nt], 0, 0, 0);
        }
    }
#pragma unroll
    for (int rt = 0; rt < 2; ++rt) {
        const int crow0 = r0 + rt * 16 + lq * 4;
#pragma unroll
        for (int nt = 0; nt < 4; ++nt) {
            int col = n0 + nt * 16 + lm;
#pragma unroll
            for (int i = 0; i < 4; ++i) {
                int r = crow0 + i;
                if (r < M) C[(size_t)r * N + col] = (bf16_t)acc[rt][nt][i];
            }
        }
    }
}

// ---------------- a_s = sum_c h[n,h,c]*att[h,c] : one wave per node ----------
__global__ __launch_bounds__(256) void att_dot(const bf16_t* __restrict__ Hb,
                                               const void* __restrict__ att,
                                               float* __restrict__ out,
                                               int Nn, int HD, int H,
                                               const int* __restrict__ flag) {
    int fp32 = flag[0];
    int wid = (blockIdx.x * 256 + threadIdx.x) >> 6;
    int lane = threadIdx.x & 63;
    if (wid >= Nn) return;
    const bf16_t* hp = Hb + (size_t)wid * HD;
    float p0 = (float)hp[lane] * ldin(att, lane, fp32);
    float p1 = 0.f;
    if (HD > 64) p1 = (float)hp[64 + lane] * ldin(att, 64 + lane, fp32);
    for (int off = 32; off; off >>= 1) {
        p0 += __shfl_down(p0, off);
        p1 += __shfl_down(p1, off);
    }
    if (lane == 0) {
        out[(size_t)wid * H] = p0;
        if (H == 2) out[(size_t)wid * H + 1] = p1;
    }
}

// ---------------- a_d[n,h] = sum_k X[n,k]*V[k,h] : one wave per node (bf16 X) -
__global__ __launch_bounds__(256) void gemv_att(const bf16_t* __restrict__ X,
                                                const float* __restrict__ V,
                                                float* __restrict__ out,
                                                int Nn, int K, int H) {
    int wid = (blockIdx.x * 256 + threadIdx.x) >> 6;
    int lane = threadIdx.x & 63;
    if (wid >= Nn) return;
    float a0 = 0.f, a1 = 0.f;
    for (int k = lane; k < K; k += 64) {
        float x = (float)X[(size_t)wid * K + k];
        if (H == 2) { a0 += x * V[k * 2]; a1 += x * V[k * 2 + 1]; }
        else a0 += x * V[k];
    }
    for (int off = 32; off; off >>= 1) {
        a0 += __shfl_down(a0, off);
        a1 += __shfl_down(a1, off);
    }
    if (lane == 0) {
        out[(size_t)wid * H] = a0;
        if (H == 2) out[(size_t)wid * H + 1] = a1;
    }
}

// ---------------- fused segment-softmax + aggregate, wave per destination ----
template<int HD, int MODE>
__global__ __launch_bounds__(256) void aggregate(const int* __restrict__ rs,
                                                 const int* __restrict__ srcs,
                                                 const float* __restrict__ as_,
                                                 const float* __restrict__ ad_,
                                                 const bf16_t* __restrict__ H,
                                                 const void* __restrict__ bias,
                                                 void* __restrict__ outb, size_t obase,
                                                 int Nd, const int* __restrict__ flag) {
    constexpr int NH = HD / 64;
    int wid = (blockIdx.x * 256 + threadIdx.x) >> 6;
    int lane = threadIdx.x & 63;
    if (wid >= Nd) return;
    int start = rs[wid], end = rs[wid + 1];
    float ad0 = ad_[(size_t)wid * NH];
    float ad1 = (NH == 2) ? ad_[(size_t)wid * NH + 1] : 0.f;
    float den0 = 0.f, den1 = 0.f;
    for (int i = start + lane; i < end; i += 64) {
        int s = srcs[i];
        float v0 = as_[(size_t)s * NH] + ad0;
        v0 = v0 > 0.f ? v0 : 0.2f * v0;
        den0 += __expf(fminf(v0, 60.f));
        if (NH == 2) {
            float v1 = as_[(size_t)s * NH + 1] + ad1;
            v1 = v1 > 0.f ? v1 : 0.2f * v1;
            den1 += __expf(fminf(v1, 60.f));
        }
    }
    for (int off = 32; off; off >>= 1) {
        den0 += __shfl_down(den0, off);
        if (NH == 2) den1 += __shfl_down(den1, off);
    }
    den0 = __shfl(den0, 0);
    float inv0 = 1.f / (den0 + 1e-16f), inv1 = 0.f;
    if (NH == 2) { den1 = __shfl(den1, 0); inv1 = 1.f / (den1 + 1e-16f); }

    float acc0 = 0.f, acc1 = 0.f;
    for (int j = start; j < end; ++j) {
        int s = srcs[j];
        if (NH == 2) {
            float v0 = as_[(size_t)s * 2] + ad0;
            v0 = v0 > 0.f ? v0 : 0.2f * v0;
            float v1 = as_[(size_t)s * 2 + 1] + ad1;
            v1 = v1 > 0.f ? v1 : 0.2f * v1;
            float e0 = __expf(fminf(v0, 60.f)) * inv0;
            float e1 = __expf(fminf(v1, 60.f)) * inv1;
            float w = (lane >> 5) ? e1 : e0;
            bf16x2 hv = *(const bf16x2*)(H + (size_t)s * 128 + 2 * lane);
            acc0 += (float)hv[0] * w;
            acc1 += (float)hv[1] * w;
        } else {
            float v0 = as_[s] + ad0;
            v0 = v0 > 0.f ? v0 : 0.2f * v0;
            float w = __expf(fminf(v0, 60.f)) * inv0;
            acc0 += (float)H[(size_t)s * 64 + lane] * w;
        }
    }
    int fp32 = flag[0];
    if (NH == 2) {
        int c0 = 2 * lane;
        float o0 = acc0 + ldin(bias, c0, fp32);
        float o1 = acc1 + ldin(bias, c0 + 1, fp32);
        bf16x2 ov;
        ov[0] = (bf16_t)fmaxf(o0, 0.f);
        ov[1] = (bf16_t)fmaxf(o1, 0.f);
        *(bf16x2*)((bf16_t*)outb + (size_t)wid * 128 + c0) = ov;
    } else {
        float o = acc0 + ldin(bias, lane, fp32);
        size_t oi = obase + (size_t)wid * 64 + lane;
        if (MODE == 0) {
            ((bf16_t*)outb)[oi] = (bf16_t)fmaxf(o, 0.f);
        } else {
            if (fp32) ((float*)outb)[oi] = o;
            else      ((bf16_t*)outb)[oi] = (bf16_t)o;
        }
    }
}

extern "C" void kernel_launch(void* const* d_in, const int* in_sizes, int n_in,
                              void* d_out, int out_size, void* d_ws, size_t ws_size,
                              hipStream_t stream) {
    const void* xc = d_in[0];
    const void* xp = d_in[1];
    const int* esrc = (const int*)d_in[2];   // customer ids
    const int* edst = (const int*)d_in[3];   // product ids
    const void* w1b_src = d_in[4];
    const void* w1b_dst = d_in[5];
    const void* a1b_src = d_in[6];
    const void* a1b_dst = d_in[7];
    const void* b1b     = d_in[8];
    const void* w1r_src = d_in[9];
    const void* w1r_dst = d_in[10];
    const void* a1r_src = d_in[11];
    const void* a1r_dst = d_in[12];
    const void* b1r     = d_in[13];
    const void* w2b_src = d_in[14];
    const void* w2b_dst = d_in[15];
    const void* a2b_src = d_in[16];
    const void* a2b_dst = d_in[17];
    const void* b2b     = d_in[18];
    const void* w2r_src = d_in[19];
    const void* w2r_dst = d_in[20];
    const void* a2r_src = d_in[21];
    const void* a2r_dst = d_in[22];
    const void* b2r     = d_in[23];

    // -------- workspace layout: NO aliasing (~167 MB, ws proven >= 199 MB) ----
    char* p = (char*)d_ws;
    auto alloc = [&](size_t nbytes) {
        char* r = p;
        p += (nbytes + 255) & ~(size_t)255;
        return r;
    };
    int* flag   = (int*)alloc(256);
    float* V1bd = (float*)alloc(256 * 4);
    float* V1rd = (float*)alloc(512 * 4);
    float* V2bd = (float*)alloc(128 * 4);
    float* V2rd = (float*)alloc(128 * 4);
    bf16_t* Wt1b = (bf16_t*)alloc(128 * 256 * 2);
    bf16_t* Wt1r = (bf16_t*)alloc(128 * 128 * 2);
    bf16_t* Wt2b = (bf16_t*)alloc(64 * 128 * 2);
    bf16_t* Wt2r = (bf16_t*)alloc(64 * 128 * 2);
    float* as_s = (float*)alloc((size_t)NCn * 2 * 4);
    float* ad_b = (float*)alloc((size_t)NPn * 2 * 4);
    float* ad_r = (float*)alloc((size_t)NCn * 2 * 4);
    int* rsB    = (int*)alloc((size_t)(NPn + 1) * 4);
    int* rsR    = (int*)alloc((size_t)(NCn + 1) * 4);
    int* srcsB  = (int*)alloc((size_t)NE * 4);
    int* srcsR  = (int*)alloc((size_t)NE * 4);
    int* cntB   = (int*)alloc((size_t)NPn * 4);
    int* cntR   = (int*)alloc((size_t)NCn * 4);
    int* bsum   = (int*)alloc(128 * 4);
    bf16_t* xcb = (bf16_t*)alloc((size_t)NCn * 256 * 2);
    bf16_t* xpb = (bf16_t*)alloc((size_t)NPn * 128 * 2);
    bf16_t* Hc  = (bf16_t*)alloc((size_t)NCn * 128 * 2);
    bf16_t* Hp  = (bf16_t*)alloc((size_t)NPn * 128 * 2);
    bf16_t* c1  = (bf16_t*)alloc((size_t)NCn * 128 * 2);
    bf16_t* p1  = (bf16_t*)alloc((size_t)NPn * 128 * 2);
    bf16_t* Hc2 = (bf16_t*)alloc((size_t)NCn * 64 * 2);
    bf16_t* Hp2 = (bf16_t*)alloc((size_t)NPn * 64 * 2);

    const dim3 blk(256);
    const int gE = (NE + 255) / 256;
    const int sbP = (NPn + 1023) / 1024;
    const int sbR = (NCn + 1023) / 1024;
    const int gmC = (NCn + 127) / 128;
    const int gmP = (NPn + 127) / 128;
    const int gNP = (NPn + 255) / 256;
    const int gNC = (NCn + 255) / 256;

    detect_dtype<<<1, 64, 0, stream>>>(xc, flag);
    prep_V<<<1, 256, 0, stream>>>(flag, w1b_dst, a1b_dst, w1r_dst, a1r_dst,
                                  w2b_dst, a2b_dst, w2r_dst, a2r_dst,
                                  V1bd, V1rd, V2bd, V2rd);
    prep_w<<<128, blk, 0, stream>>>(w1b_src, Wt1b, 128, 8, flag);
    prep_w<<<64,  blk, 0, stream>>>(w1r_src, Wt1r, 128, 7, flag);
    prep_w<<<32,  blk, 0, stream>>>(w2b_src, Wt2b, 64, 7, flag);
    prep_w<<<32,  blk, 0, stream>>>(w2r_src, Wt2r, 64, 7, flag);

    // -------- CSR build dir b (dst = product) --------
    zero_int<<<gNP, blk, 0, stream>>>(cntB, NPn);
    hist_k<<<gE, blk, 0, stream>>>(edst, cntB, NE);
    scan_blocks<<<sbP, blk, 0, stream>>>(cntB, rsB, bsum, NPn);
    scan_bsum<<<1, 128, 0, stream>>>(bsum, sbP);
    scan_add<<<gNP + 1, blk, 0, stream>>>(rsB, bsum, NPn, NE);
    copy_int<<<gNP, blk, 0, stream>>>(rsB, cntB, NPn);
    scatter_k<<<gE, blk, 0, stream>>>(edst, esrc, cntB, srcsB, NE);

    // -------- CSR build dir r (dst = customer) --------
    zero_int<<<gNC, blk, 0, stream>>>(cntR, NCn);
    hist_k<<<gE, blk, 0, stream>>>(esrc, cntR, NE);
    scan_blocks<<<sbR, blk, 0, stream>>>(cntR, rsR, bsum, NCn);
    scan_bsum<<<1, 128, 0, stream>>>(bsum, sbR);
    scan_add<<<gNC + 1, blk, 0, stream>>>(rsR, bsum, NCn, NE);
    copy_int<<<gNC, blk, 0, stream>>>(rsR, cntR, NCn);
    scatter_k<<<gE, blk, 0, stream>>>(esrc, edst, cntR, srcsR, NE);

    // -------- convert inputs to bf16 + fused L1 dst scores --------
    cvt_rows<256><<<(NCn + 3) / 4, blk, 0, stream>>>(xc, xcb, V1rd, ad_r, NCn, flag);
    cvt_rows<128><<<(NPn + 3) / 4, blk, 0, stream>>>(xp, xpb, V1bd, ad_b, NPn, flag);

    // -------- layer 1 src projections --------
    gemm_nl<256><<<dim3(gmC, 2), blk, 0, stream>>>(xcb, Wt1b, Hc, NCn, 128);
    gemm_nl<128><<<dim3(gmP, 2), blk, 0, stream>>>(xpb, Wt1r, Hp, NPn, 128);

    // ---- L1 dir b (customer -> product) -> p1 ----
    att_dot<<<(NCn + 3) / 4, blk, 0, stream>>>(Hc, a1b_src, as_s, NCn, 128, 2, flag);
    aggregate<128, 0><<<(NPn + 3) / 4, blk, 0, stream>>>(rsB, srcsB, as_s, ad_b, Hc, b1b, p1, 0, NPn, flag);

    // ---- L1 dir r (product -> customer) -> c1 ----
    att_dot<<<(NPn + 3) / 4, blk, 0, stream>>>(Hp, a1r_src, as_s, NPn, 128, 2, flag);
    aggregate<128, 0><<<(NCn + 3) / 4, blk, 0, stream>>>(rsR, srcsR, as_s, ad_r, Hp, b1r, c1, 0, NCn, flag);

    // -------- layer 2 src projections --------
    gemm_nl<128><<<dim3(gmC, 1), blk, 0, stream>>>(c1, Wt2b, Hc2, NCn, 64);
    gemm_nl<128><<<dim3(gmP, 1), blk, 0, stream>>>(p1, Wt2r, Hp2, NPn, 64);

    // ---- L2 dir b -> p2 (second half of d_out) ----
    att_dot<<<(NCn + 3) / 4, blk, 0, stream>>>(Hc2, a2b_src, as_s, NCn, 64, 1, flag);
    gemv_att<<<(NPn + 3) / 4, blk, 0, stream>>>(p1, V2bd, ad_b, NPn, 128, 1);
    aggregate<64, 1><<<(NPn + 3) / 4, blk, 0, stream>>>(rsB, srcsB, as_s, ad_b, Hc2, b2b, d_out, (size_t)NCn * 64, NPn, flag);

    // ---- L2 dir r -> c2 (first half of d_out) ----
    att_dot<<<(NPn + 3) / 4, blk, 0, stream>>>(Hp2, a2r_src, as_s, NPn, 64, 1, flag);
    gemv_att<<<(NCn + 3) / 4, blk, 0, stream>>>(c1, V2rd, ad_r, NCn, 128, 1);
    aggregate<64, 1><<<(NCn + 3) / 4, blk, 0, stream>>>(rsR, srcsR, as_s, ad_r, Hp2, b2r, d_out, 0, NCn, flag);
}